// Round 1
// baseline (63810.822 us; speedup 1.0000x reference)
//
#include <hip/hip_runtime.h>
#include <stdint.h>

// Problem constants (from reference)
#define BATCH 4096
#define RNN   512
#define SEGS  512

typedef __attribute__((ext_vector_type(8))) short bf16x8;
typedef __attribute__((ext_vector_type(4))) float f32x4;

#define MODE_TANH  0
#define MODE_BASE  1
#define MODE_CELL1 2
#define MODE_CELL2 3

__device__ __forceinline__ unsigned short f2bf(float f){
  unsigned u = __float_as_uint(f);
  u += 0x7FFF + ((u >> 16) & 1);   // RNE
  return (unsigned short)(u >> 16);
}
__device__ __forceinline__ float bf2f(unsigned short s){
  return __uint_as_float(((unsigned)s) << 16);
}
__device__ __forceinline__ float fsigmoid(float x){ return 1.0f / (1.0f + __expf(-x)); }
__device__ __forceinline__ float ftanh(float x){
  float e = __expf(-2.0f * fabsf(x));
  float t = (1.0f - e) / (1.0f + e);
  return copysignf(t, x);
}

// ---------------- prep kernels ----------------

__global__ void prep_cvt(const float* __restrict__ x, short* __restrict__ y, int n){
  int i = blockIdx.x * 256 + threadIdx.x;
  if (i < n) y[i] = (short)f2bf(x[i]);
}

// Reorder gate rows: new row 4*j+g  <-  old row g*512+j  (gate order i,f,g,o)
__global__ void prep_reorder(
    const float* __restrict__ W_ih1, const float* __restrict__ W_hh1,
    const float* __restrict__ b_ih1, const float* __restrict__ b_hh1,
    const float* __restrict__ W_ih2, const float* __restrict__ W_hh2,
    const float* __restrict__ b_ih2, const float* __restrict__ b_hh2,
    short* __restrict__ Wr1, short* __restrict__ W1c,
    short* __restrict__ Wr2i, short* __restrict__ Wr2h,
    float* __restrict__ w1r, float* __restrict__ b1r, float* __restrict__ b2r)
{
  int idx = blockIdx.x * 256 + threadIdx.x;   // over 2048*512
  if (idx >= 2048 * 512) return;
  int rn = idx >> 9;        // new row
  int k  = idx & 511;
  int j = rn >> 2, g = rn & 3;
  int ro = g * 512 + j;     // old row
  Wr1 [idx] = (short)f2bf(W_hh1[(size_t)ro * 512 + k]);
  W1c [idx] = (short)f2bf(W_ih1[(size_t)ro * 514 + k]);   // W_ih1 rows are length 514
  Wr2i[idx] = (short)f2bf(W_ih2[(size_t)ro * 512 + k]);
  Wr2h[idx] = (short)f2bf(W_hh2[(size_t)ro * 512 + k]);
  if (k == 0){
    w1r[rn] = W_ih1[(size_t)ro * 514 + 512];  // the "angles" input column
    b1r[rn] = b_ih1[ro] + b_hh1[ro];
    b2r[rn] = b_ih2[ro] + b_hh2[ro];
  }
}

// ---------------- fused bf16 MFMA GEMM ----------------
// C[m,n] = sum_k A[m,k]*B[n,k]   (B stored [N,K] row-major, K=512 rows)
// Supports a second (A2,B2) pair accumulated into the same C (for K=1024 phase B).
// Epilogues: tanh+store-bf16 / +bias store-f32 / fused LSTM cell (gate-interleaved cols).
__global__ __launch_bounds__(256) void gemm_fused(
    const short* __restrict__ A1, const short* __restrict__ B1,
    const short* __restrict__ A2, const short* __restrict__ B2,
    int k1, int k2, int N, int mode,
    const float* __restrict__ bias,
    const float* __restrict__ base1,
    const float* __restrict__ w1r,
    const float* __restrict__ ang,
    float* __restrict__ cbuf,
    void* __restrict__ outp)
{
  __shared__ __align__(16) short As[128 * 72];   // +8 pad: 2-way LDS conflicts only (free)
  __shared__ __align__(16) short Bs[128 * 72];
  const int tid  = threadIdx.x;
  const int lane = tid & 63;
  const int wave = tid >> 6;
  const int wm = wave >> 1, wn = wave & 1;       // 2x2 waves of 64x64
  const int m0 = blockIdx.y * 128, n0 = blockIdx.x * 128;

  f32x4 acc[4][4];
  #pragma unroll
  for (int i = 0; i < 4; i++)
    #pragma unroll
    for (int j = 0; j < 4; j++)
      acc[i][j] = (f32x4){0.f, 0.f, 0.f, 0.f};

  const int nk = (k1 + k2) >> 6;
  for (int it = 0; it < nk; ++it){
    int ko = it << 6;
    const short* Ap; const short* Bp; int kk;
    if (ko < k1){ Ap = A1; Bp = B1; kk = ko; }
    else        { Ap = A2; Bp = B2; kk = ko - k1; }
    #pragma unroll
    for (int i = 0; i < 4; i++){
      int c = i * 256 + tid;                 // 1024 16B-chunks per tile
      int row = c >> 3, c8 = (c & 7) << 3;
      *(uint4*)&As[row * 72 + c8] = *(const uint4*)&Ap[(size_t)(m0 + row) * 512 + kk + c8];
      *(uint4*)&Bs[row * 72 + c8] = *(const uint4*)&Bp[(size_t)(n0 + row) * 512 + kk + c8];
    }
    __syncthreads();
    #pragma unroll
    for (int kw = 0; kw < 2; ++kw){
      bf16x8 af[4], bfr[4];
      const int ro = (lane & 15) * 72 + kw * 32 + (lane >> 4) * 8;
      #pragma unroll
      for (int f = 0; f < 4; f++){
        af[f]  = *(const bf16x8*)&As[(wm * 64 + f * 16) * 72 + ro];
        bfr[f] = *(const bf16x8*)&Bs[(wn * 64 + f * 16) * 72 + ro];
      }
      #pragma unroll
      for (int mf = 0; mf < 4; mf++)
        #pragma unroll
        for (int nf = 0; nf < 4; nf++)
          acc[mf][nf] = __builtin_amdgcn_mfma_f32_16x16x32_bf16(af[mf], bfr[nf], acc[mf][nf], 0, 0, 0);
    }
    __syncthreads();
  }

  const int lr = (lane >> 4) * 4;   // C row = quad*4 + reg
  const int lc = lane & 15;         // C col = lane&15

  if (mode == MODE_TANH){
    unsigned short* out = (unsigned short*)outp;
    #pragma unroll
    for (int mf = 0; mf < 4; mf++)
      #pragma unroll
      for (int nf = 0; nf < 4; nf++)
        #pragma unroll
        for (int r = 0; r < 4; r++){
          int grow = m0 + wm * 64 + mf * 16 + lr + r;
          int gcol = n0 + wn * 64 + nf * 16 + lc;
          float v = acc[mf][nf][r] + bias[gcol];
          out[(size_t)grow * N + gcol] = f2bf(ftanh(v));
        }
  } else if (mode == MODE_BASE){
    float* out = (float*)outp;
    #pragma unroll
    for (int mf = 0; mf < 4; mf++)
      #pragma unroll
      for (int nf = 0; nf < 4; nf++)
        #pragma unroll
        for (int r = 0; r < 4; r++){
          int grow = m0 + wm * 64 + mf * 16 + lr + r;
          int gcol = n0 + wn * 64 + nf * 16 + lc;
          out[(size_t)grow * N + gcol] = acc[mf][nf][r] + bias[gcol];
        }
  } else {
    // Fused LSTM cell: cols are gate-interleaved (col = 4*j + g, g in {i,f,g,o}).
    // Lanes l, l^1, l^2, l^3 hold the 4 gates of the same hidden unit.
    unsigned short* hout = (unsigned short*)outp;
    const int q = lane & 3;
    #pragma unroll
    for (int mf = 0; mf < 4; mf++)
      #pragma unroll
      for (int nf = 0; nf < 4; nf++)
        #pragma unroll
        for (int r = 0; r < 4; r++){
          int grow = m0 + wm * 64 + mf * 16 + lr + r;
          int gcol = n0 + wn * 64 + nf * 16 + lc;
          float v = acc[mf][nf][r];
          if (mode == MODE_CELL1)
            v += base1[(size_t)grow * 2048 + gcol] + ang[grow] * w1r[gcol];
          else
            v += bias[gcol];
          float x1 = __shfl_xor(v, 1);
          float x2 = __shfl_xor(v, 2);
          float x3 = __shfl_xor(v, 3);
          if (q == 0){
            // xs[k] = value from lane^k; gates i,f,g,o at xs[0..3]
            int j = gcol >> 2;
            size_t ci = (size_t)grow * 512 + j;
            float co = cbuf[ci];
            float cn = fsigmoid(x1) * co + fsigmoid(v) * ftanh(x2);
            float hn = fsigmoid(x3) * ftanh(cn);
            cbuf[ci] = cn;
            hout[ci] = f2bf(hn);
          }
        }
  }
}

// ---------------- head: mixture + rsample + tanh ----------------
// One wave per batch row. 15 dots of length 512, butterfly-reduced.
__global__ __launch_bounds__(256) void head_step(
    const short* __restrict__ h2,
    const float* __restrict__ Wmu,  const float* __restrict__ bmu,
    const float* __restrict__ Wvar, const float* __restrict__ bvar,
    const float* __restrict__ Wmix, const float* __restrict__ bmix,
    const float* __restrict__ eps,  float* __restrict__ ang,
    float* __restrict__ out, int s)
{
  const int lane = threadIdx.x & 63;
  const int wave = threadIdx.x >> 6;
  const int row = blockIdx.x * 4 + wave;

  uint4 hv = *(const uint4*)&h2[(size_t)row * 512 + lane * 8];
  const unsigned short* hs = (const unsigned short*)&hv;
  float h[8];
  #pragma unroll
  for (int j = 0; j < 8; j++) h[j] = bf2f(hs[j]);

  float p[15];
  #pragma unroll
  for (int k = 0; k < 5; k++){
    const float4* wm4 = (const float4*)(Wmu  + (size_t)k * 512 + lane * 8);
    const float4* wv4 = (const float4*)(Wvar + (size_t)k * 512 + lane * 8);
    const float4* wx4 = (const float4*)(Wmix + (size_t)k * 512 + lane * 8);
    float4 a0 = wm4[0], a1 = wm4[1];
    float4 v0 = wv4[0], v1 = wv4[1];
    float4 x0 = wx4[0], x1 = wx4[1];
    p[k]      = h[0]*a0.x + h[1]*a0.y + h[2]*a0.z + h[3]*a0.w + h[4]*a1.x + h[5]*a1.y + h[6]*a1.z + h[7]*a1.w;
    p[5 + k]  = h[0]*v0.x + h[1]*v0.y + h[2]*v0.z + h[3]*v0.w + h[4]*v1.x + h[5]*v1.y + h[6]*v1.z + h[7]*v1.w;
    p[10 + k] = h[0]*x0.x + h[1]*x0.y + h[2]*x0.z + h[3]*x0.w + h[4]*x1.x + h[5]*x1.y + h[6]*x1.z + h[7]*x1.w;
  }
  #pragma unroll
  for (int k = 0; k < 15; k++){
    #pragma unroll
    for (int off = 1; off < 64; off <<= 1)
      p[k] += __shfl_xor(p[k], off);
  }
  if (lane == 0){
    float l[5], mx = -1e30f;
    #pragma unroll
    for (int k = 0; k < 5; k++){ l[k] = p[10 + k] + bmix[k]; mx = fmaxf(mx, l[k]); }
    float se = 0.f, e[5];
    #pragma unroll
    for (int k = 0; k < 5; k++){ e[k] = __expf(l[k] - mx); se += e[k]; }
    float inv = 1.0f / se, mu = 0.f, sg = 0.f;
    #pragma unroll
    for (int k = 0; k < 5; k++){
      float rho = e[k] * inv;
      mu += rho * (p[k] + bmu[k]);
      sg += rho * __expf(p[5 + k] + bvar[k]);   // t = 0
    }
    float a = ftanh(mu + sg * eps[(size_t)s * BATCH + row]);
    ang[row] = a;
    size_t o = ((size_t)row * SEGS + s) * 2;
    out[o]     = a;
    out[o + 1] = 0.0f;
  }
}

// ---------------- launch ----------------

extern "C" void kernel_launch(void* const* d_in, const int* in_sizes, int n_in,
                              void* d_out, int out_size, void* d_ws, size_t ws_size,
                              hipStream_t stream)
{
  const float* latent   = (const float*)d_in[0];
  const float* W_unpack = (const float*)d_in[1];
  const float* b_unpack = (const float*)d_in[2];
  const float* W_ih1    = (const float*)d_in[3];
  const float* W_hh1    = (const float*)d_in[4];
  const float* b_ih1    = (const float*)d_in[5];
  const float* b_hh1    = (const float*)d_in[6];
  const float* W_ih2    = (const float*)d_in[7];
  const float* W_hh2    = (const float*)d_in[8];
  const float* b_ih2    = (const float*)d_in[9];
  const float* b_hh2    = (const float*)d_in[10];
  const float* W_mu     = (const float*)d_in[11];
  const float* b_mu     = (const float*)d_in[12];
  const float* W_var    = (const float*)d_in[13];
  const float* b_var    = (const float*)d_in[14];
  const float* W_mix    = (const float*)d_in[15];
  const float* b_mix    = (const float*)d_in[16];
  const float* eps      = (const float*)d_in[17];
  float* out = (float*)d_out;

  char* p = (char*)d_ws;
  auto alloc = [&](size_t b) -> void* {
    void* r = (void*)p;
    p += (b + 255) & ~(size_t)255;
    return r;
  };
  short* latb  = (short*)alloc((size_t)BATCH * 512 * 2);
  short* Wub   = (short*)alloc((size_t)512 * 512 * 2);
  short* idea  = (short*)alloc((size_t)BATCH * 512 * 2);
  float* base1 = (float*)alloc((size_t)BATCH * 2048 * 4);
  short* Wr1   = (short*)alloc((size_t)2048 * 512 * 2);
  short* W1c   = (short*)alloc((size_t)2048 * 512 * 2);
  short* Wr2i  = (short*)alloc((size_t)2048 * 512 * 2);
  short* Wr2h  = (short*)alloc((size_t)2048 * 512 * 2);
  float* w1r   = (float*)alloc(2048 * 4);
  float* b1r   = (float*)alloc(2048 * 4);
  float* b2r   = (float*)alloc(2048 * 4);
  short* h1a   = (short*)alloc((size_t)BATCH * 512 * 2);
  short* h1b   = (short*)alloc((size_t)BATCH * 512 * 2);
  short* h2a   = (short*)alloc((size_t)BATCH * 512 * 2);
  short* h2b   = (short*)alloc((size_t)BATCH * 512 * 2);
  float* c1    = (float*)alloc((size_t)BATCH * 512 * 4);
  float* c2    = (float*)alloc((size_t)BATCH * 512 * 4);
  float* ang   = (float*)alloc(BATCH * 4);
  short* h1[2] = {h1a, h1b};
  short* h2[2] = {h2a, h2b};

  hipMemsetAsync(h1[0], 0, (size_t)BATCH * 512 * 2, stream);
  hipMemsetAsync(h2[0], 0, (size_t)BATCH * 512 * 2, stream);
  hipMemsetAsync(c1, 0, (size_t)BATCH * 512 * 4, stream);
  hipMemsetAsync(c2, 0, (size_t)BATCH * 512 * 4, stream);
  hipMemsetAsync(ang, 0, BATCH * 4, stream);

  prep_cvt<<<(BATCH * 512) / 256, 256, 0, stream>>>(latent, latb, BATCH * 512);
  prep_cvt<<<(512 * 512) / 256, 256, 0, stream>>>(W_unpack, Wub, 512 * 512);
  prep_reorder<<<(2048 * 512) / 256, 256, 0, stream>>>(
      W_ih1, W_hh1, b_ih1, b_hh1, W_ih2, W_hh2, b_ih2, b_hh2,
      Wr1, W1c, Wr2i, Wr2h, w1r, b1r, b2r);

  dim3 blk(256);
  // idea = tanh(latent @ W_unpack^T + b_unpack)  [bf16]
  gemm_fused<<<dim3(512 / 128, 32), blk, 0, stream>>>(
      latb, Wub, nullptr, nullptr, 512, 0, 512, MODE_TANH,
      b_unpack, nullptr, nullptr, nullptr, nullptr, (void*)idea);
  // base1 = idea @ W1c^T + (b_ih1 + b_hh1)   [fp32, gate-interleaved cols]
  gemm_fused<<<dim3(2048 / 128, 32), blk, 0, stream>>>(
      idea, W1c, nullptr, nullptr, 512, 0, 2048, MODE_BASE,
      b1r, nullptr, nullptr, nullptr, nullptr, (void*)base1);

  int cur = 0;
  for (int s = 0; s < SEGS; ++s){
    // gates1 = base1 + ang*w1r + h1 @ Wr1^T  -> cell1 -> h1', c1
    gemm_fused<<<dim3(16, 32), blk, 0, stream>>>(
        h1[cur], Wr1, nullptr, nullptr, 512, 0, 2048, MODE_CELL1,
        nullptr, base1, w1r, ang, c1, (void*)h1[cur ^ 1]);
    // gates2 = b2r + h1' @ Wr2i^T + h2 @ Wr2h^T -> cell2 -> h2', c2
    gemm_fused<<<dim3(16, 32), blk, 0, stream>>>(
        h1[cur ^ 1], Wr2i, h2[cur], Wr2h, 512, 512, 2048, MODE_CELL2,
        b2r, nullptr, nullptr, nullptr, c2, (void*)h2[cur ^ 1]);
    // mixture head + rsample + tanh -> angles, out[:, s, :]
    head_step<<<BATCH / 4, 256, 0, stream>>>(
        h2[cur ^ 1], W_mu, b_mu, W_var, b_var, W_mix, b_mix, eps, ang, out, s);
    cur ^= 1;
  }
}

// Round 2
// 61065.228 us; speedup vs baseline: 1.0450x; 1.0450x over previous
//
#include <hip/hip_runtime.h>
#include <stdint.h>

#define BATCH 4096
#define RNN   512
#define SEGS  512

typedef __attribute__((ext_vector_type(8))) short bf16x8;
typedef __attribute__((ext_vector_type(4))) float f32x4;

#define MODE_TANH  0
#define MODE_BASE  1
#define MODE_CELL1 2
#define MODE_CELL2 3

#define GLD_LDS16(g, l) \
  __builtin_amdgcn_global_load_lds((const __attribute__((address_space(1))) void*)(g), \
                                   (__attribute__((address_space(3))) void*)(l), 16, 0, 0)

__device__ __forceinline__ unsigned short f2bf(float f){
  unsigned u = __float_as_uint(f);
  u += 0x7FFF + ((u >> 16) & 1);   // RNE
  return (unsigned short)(u >> 16);
}
__device__ __forceinline__ float bf2f(unsigned short s){
  return __uint_as_float(((unsigned)s) << 16);
}
__device__ __forceinline__ float fsigmoid(float x){ return 1.0f / (1.0f + __expf(-x)); }
__device__ __forceinline__ float ftanh(float x){
  float e = __expf(-2.0f * fabsf(x));
  float t = (1.0f - e) / (1.0f + e);
  return copysignf(t, x);
}

// ---------------- prep kernels ----------------

__global__ void prep_cvt(const float* __restrict__ x, short* __restrict__ y, int n){
  int i = blockIdx.x * 256 + threadIdx.x;
  if (i < n) y[i] = (short)f2bf(x[i]);
}

// Reorder gate rows: new row 4*j+g  <-  old row g*512+j  (gate order i,f,g,o)
__global__ void prep_reorder(
    const float* __restrict__ W_ih1, const float* __restrict__ W_hh1,
    const float* __restrict__ b_ih1, const float* __restrict__ b_hh1,
    const float* __restrict__ W_ih2, const float* __restrict__ W_hh2,
    const float* __restrict__ b_ih2, const float* __restrict__ b_hh2,
    short* __restrict__ Wr1, short* __restrict__ W1c,
    short* __restrict__ Wr2i, short* __restrict__ Wr2h,
    float* __restrict__ w1r, float* __restrict__ b1r, float* __restrict__ b2r)
{
  int idx = blockIdx.x * 256 + threadIdx.x;   // over 2048*512
  if (idx >= 2048 * 512) return;
  int rn = idx >> 9;        // new row
  int k  = idx & 511;
  int j = rn >> 2, g = rn & 3;
  int ro = g * 512 + j;     // old row
  Wr1 [idx] = (short)f2bf(W_hh1[(size_t)ro * 512 + k]);
  W1c [idx] = (short)f2bf(W_ih1[(size_t)ro * 514 + k]);   // W_ih1 rows are length 514
  Wr2i[idx] = (short)f2bf(W_ih2[(size_t)ro * 512 + k]);
  Wr2h[idx] = (short)f2bf(W_hh2[(size_t)ro * 512 + k]);
  if (k == 0){
    w1r[rn] = W_ih1[(size_t)ro * 514 + 512];  // the "angles" input column
    b1r[rn] = b_ih1[ro] + b_hh1[ro];
    b2r[rn] = b_ih2[ro] + b_hh2[ro];
  }
}

// Pack head weights: Wh[16][512] bf16, rows 0-4 Wmu, 5-9 Wvar, 10-14 Wmix, 15 zero
__global__ void prep_whead(const float* __restrict__ Wmu, const float* __restrict__ Wvar,
                           const float* __restrict__ Wmix, short* __restrict__ Wh){
  int i = blockIdx.x * 256 + threadIdx.x;   // 16*512
  if (i >= 16 * 512) return;
  int n = i >> 9, k = i & 511;
  float v = (n < 5) ? Wmu[n * 512 + k] : (n < 10) ? Wvar[(n - 5) * 512 + k]
          : (n < 15) ? Wmix[(n - 10) * 512 + k] : 0.f;
  Wh[i] = (short)f2bf(v);
}

// ---------------- fused bf16 MFMA GEMM ----------------
// C[m,n] = sum_k A[m,k]*B[n,k]   (B stored [N,K] row-major)
// Staging: global_load_lds width=16, fragment-ordered LDS layout:
//   16B chunk c = ((g*2+kw)*16 + r16)*4 + quad  maps to  A[g*16+r16][kw*32+quad*8 ..+8]
//   -> fragment ds_read_b128: 64 lanes read one contiguous 1KB block (conflict-free)
//   -> staging: per-issue 64 chunks = 16 rows x 64B segments (lane order matches dest)
__global__ __launch_bounds__(256) void gemm_fused(
    const short* __restrict__ A1, const short* __restrict__ B1,
    const short* __restrict__ A2, const short* __restrict__ B2,
    int k1, int k2, int N, int mode,
    const float* __restrict__ bias,
    const unsigned short* __restrict__ base1,  // bf16
    const float* __restrict__ w1r,
    float* __restrict__ cbuf,
    void* __restrict__ outp,
    // fused head (MODE_CELL1 only):
    const short* __restrict__ h2prev, const short* __restrict__ Whead,
    const float* __restrict__ bmu, const float* __restrict__ bvar,
    const float* __restrict__ bmix, const float* __restrict__ eps,
    float* __restrict__ fout, int s)
{
  __shared__ __align__(16) short As[8192];       // 8 groups x 2 kw x 512 elems
  __shared__ __align__(16) short Bs[8192];
  __shared__ __align__(16) float headP[128 * 16];
  __shared__ float angS[128];

  const int tid  = threadIdx.x;
  const int lane = tid & 63;
  const int wave = tid >> 6;
  const int wm = wave >> 1, wn = wave & 1;       // 2x2 waves of 64x64
  const int m0 = blockIdx.y * 128, n0 = blockIdx.x * 128;

  // per-thread staging source offsets (element units), loop-invariant part
  int aoff[4], boff[4];
  #pragma unroll
  for (int j = 0; j < 4; j++){
    int c = (wave * 4 + j) * 64 + lane;          // chunk index 0..1023
    int quad = c & 3, r16 = (c >> 2) & 15, kw = (c >> 6) & 1, g = c >> 7;
    int row = g * 16 + r16, col = kw * 32 + quad * 8;
    aoff[j] = (m0 + row) * 512 + col;
    boff[j] = (n0 + row) * 512 + col;
  }

  f32x4 acc[4][4];
  #pragma unroll
  for (int i = 0; i < 4; i++)
    #pragma unroll
    for (int j = 0; j < 4; j++)
      acc[i][j] = (f32x4){0.f, 0.f, 0.f, 0.f};

  const int nk = (k1 + k2) >> 6;

  auto stage = [&](int it){
    int ko = it << 6;
    const short* Ap; const short* Bp; int kk;
    if (ko < k1){ Ap = A1; Bp = B1; kk = ko; }
    else        { Ap = A2; Bp = B2; kk = ko - k1; }
    #pragma unroll
    for (int j = 0; j < 4; j++){
      GLD_LDS16(Ap + aoff[j] + kk, (char*)As + (wave * 4 + j) * 1024);
      GLD_LDS16(Bp + boff[j] + kk, (char*)Bs + (wave * 4 + j) * 1024);
    }
  };

  const int fro = ((lane & 15) * 4 + (lane >> 4)) * 8;  // elem offset in (g,kw) block

  auto compute = [&](){
    #pragma unroll
    for (int kw = 0; kw < 2; ++kw){
      bf16x8 af[4], bfr[4];
      #pragma unroll
      for (int f = 0; f < 4; f++){
        af[f]  = *(const bf16x8*)&As[((wm * 4 + f) * 2 + kw) * 512 + fro];
        bfr[f] = *(const bf16x8*)&Bs[((wn * 4 + f) * 2 + kw) * 512 + fro];
      }
      #pragma unroll
      for (int mf = 0; mf < 4; mf++)
        #pragma unroll
        for (int nf = 0; nf < 4; nf++)
          acc[mf][nf] = __builtin_amdgcn_mfma_f32_16x16x32_bf16(af[mf], bfr[nf], acc[mf][nf], 0, 0, 0);
    }
  };

  // ---- iteration 0 staged first; fused head overlaps the in-flight loads ----
  stage(0);

  if (mode == MODE_CELL1 && s > 0){
    // P[128x16] = h2prev[m0..m0+127] @ Whead^T via MFMA; wave handles 2 row-groups
    const int g0 = wave * 2;
    f32x4 pa0 = {0.f,0.f,0.f,0.f}, pa1 = {0.f,0.f,0.f,0.f};
    const int arow = m0 + g0 * 16 + (lane & 15);
    const int koff = (lane >> 4) * 8;
    #pragma unroll
    for (int k0 = 0; k0 < 512; k0 += 32){
      bf16x8 bfh = *(const bf16x8*)&Whead[(lane & 15) * 512 + k0 + koff];
      bf16x8 a0  = *(const bf16x8*)&h2prev[(size_t)arow * 512 + k0 + koff];
      bf16x8 a1  = *(const bf16x8*)&h2prev[(size_t)(arow + 16) * 512 + k0 + koff];
      pa0 = __builtin_amdgcn_mfma_f32_16x16x32_bf16(a0, bfh, pa0, 0, 0, 0);
      pa1 = __builtin_amdgcn_mfma_f32_16x16x32_bf16(a1, bfh, pa1, 0, 0, 0);
    }
    #pragma unroll
    for (int r = 0; r < 4; r++){
      headP[((g0    ) * 16 + (lane >> 4) * 4 + r) * 16 + (lane & 15)] = pa0[r];
      headP[((g0 + 1) * 16 + (lane >> 4) * 4 + r) * 16 + (lane & 15)] = pa1[r];
    }
  }

  __syncthreads();   // drains stage(0) loads + headP stores

  if (mode == MODE_CELL1){
    if (s > 0){
      if (tid < 128){
        float p[15];
        #pragma unroll
        for (int k = 0; k < 15; k++) p[k] = headP[tid * 16 + k];
        float l[5], mx = -1e30f;
        #pragma unroll
        for (int k = 0; k < 5; k++){ l[k] = p[10 + k] + bmix[k]; mx = fmaxf(mx, l[k]); }
        float se = 0.f, e[5];
        #pragma unroll
        for (int k = 0; k < 5; k++){ e[k] = __expf(l[k] - mx); se += e[k]; }
        float inv = 1.0f / se, mu = 0.f, sg = 0.f;
        #pragma unroll
        for (int k = 0; k < 5; k++){
          float rho = e[k] * inv;
          mu += rho * (p[k] + bmu[k]);
          sg += rho * __expf(p[5 + k] + bvar[k]);
        }
        float a = ftanh(mu + sg * eps[(size_t)(s - 1) * BATCH + m0 + tid]);
        angS[tid] = a;
        if (blockIdx.x == 0){
          size_t o = ((size_t)(m0 + tid) * SEGS + (s - 1)) * 2;
          fout[o] = a; fout[o + 1] = 0.0f;
        }
      }
    } else if (tid < 128) angS[tid] = 0.f;
  }

  compute();          // iteration 0
  __syncthreads();

  for (int it = 1; it < nk; ++it){
    stage(it);
    __syncthreads();
    compute();
    __syncthreads();
  }

  const int lr = (lane >> 4) * 4;   // C row = quad*4 + reg
  const int lc = lane & 15;         // C col = lane&15

  if (mode == MODE_TANH){
    unsigned short* out = (unsigned short*)outp;
    #pragma unroll
    for (int mf = 0; mf < 4; mf++)
      #pragma unroll
      for (int nf = 0; nf < 4; nf++)
        #pragma unroll
        for (int r = 0; r < 4; r++){
          int grow = m0 + wm * 64 + mf * 16 + lr + r;
          int gcol = n0 + wn * 64 + nf * 16 + lc;
          float v = acc[mf][nf][r] + bias[gcol];
          out[(size_t)grow * N + gcol] = f2bf(ftanh(v));
        }
  } else if (mode == MODE_BASE){
    unsigned short* out = (unsigned short*)outp;
    #pragma unroll
    for (int mf = 0; mf < 4; mf++)
      #pragma unroll
      for (int nf = 0; nf < 4; nf++)
        #pragma unroll
        for (int r = 0; r < 4; r++){
          int grow = m0 + wm * 64 + mf * 16 + lr + r;
          int gcol = n0 + wn * 64 + nf * 16 + lc;
          out[(size_t)grow * N + gcol] = f2bf(acc[mf][nf][r] + bias[gcol]);
        }
  } else {
    // Fused LSTM cell: cols gate-interleaved (col = 4*j + g, gates i,f,g,o)
    unsigned short* hout = (unsigned short*)outp;
    const int q = lane & 3;
    #pragma unroll
    for (int mf = 0; mf < 4; mf++)
      #pragma unroll
      for (int nf = 0; nf < 4; nf++)
        #pragma unroll
        for (int r = 0; r < 4; r++){
          int grow = m0 + wm * 64 + mf * 16 + lr + r;
          int gcol = n0 + wn * 64 + nf * 16 + lc;
          float v = acc[mf][nf][r];
          if (mode == MODE_CELL1)
            v += bf2f(base1[(size_t)grow * 2048 + gcol]) + angS[grow - m0] * w1r[gcol];
          else
            v += bias[gcol];
          float x1 = __shfl_xor(v, 1);
          float x2 = __shfl_xor(v, 2);
          float x3 = __shfl_xor(v, 3);
          if (q == 0){
            int j = gcol >> 2;
            size_t ci = (size_t)grow * 512 + j;
            float co = cbuf[ci];
            float cn = fsigmoid(x1) * co + fsigmoid(v) * ftanh(x2);
            float hn = fsigmoid(x3) * ftanh(cn);
            cbuf[ci] = cn;
            hout[ci] = f2bf(hn);
          }
        }
  }
}

// ---------------- head (tail step only) ----------------
__global__ __launch_bounds__(256) void head_step(
    const short* __restrict__ h2,
    const float* __restrict__ Wmu,  const float* __restrict__ bmu,
    const float* __restrict__ Wvar, const float* __restrict__ bvar,
    const float* __restrict__ Wmix, const float* __restrict__ bmix,
    const float* __restrict__ eps,  float* __restrict__ ang,
    float* __restrict__ out, int s)
{
  const int lane = threadIdx.x & 63;
  const int wave = threadIdx.x >> 6;
  const int row = blockIdx.x * 4 + wave;

  uint4 hv = *(const uint4*)&h2[(size_t)row * 512 + lane * 8];
  const unsigned short* hs = (const unsigned short*)&hv;
  float h[8];
  #pragma unroll
  for (int j = 0; j < 8; j++) h[j] = bf2f(hs[j]);

  float p[15];
  #pragma unroll
  for (int k = 0; k < 5; k++){
    const float4* wm4 = (const float4*)(Wmu  + (size_t)k * 512 + lane * 8);
    const float4* wv4 = (const float4*)(Wvar + (size_t)k * 512 + lane * 8);
    const float4* wx4 = (const float4*)(Wmix + (size_t)k * 512 + lane * 8);
    float4 a0 = wm4[0], a1 = wm4[1];
    float4 v0 = wv4[0], v1 = wv4[1];
    float4 x0 = wx4[0], x1 = wx4[1];
    p[k]      = h[0]*a0.x + h[1]*a0.y + h[2]*a0.z + h[3]*a0.w + h[4]*a1.x + h[5]*a1.y + h[6]*a1.z + h[7]*a1.w;
    p[5 + k]  = h[0]*v0.x + h[1]*v0.y + h[2]*v0.z + h[3]*v0.w + h[4]*v1.x + h[5]*v1.y + h[6]*v1.z + h[7]*v1.w;
    p[10 + k] = h[0]*x0.x + h[1]*x0.y + h[2]*x0.z + h[3]*x0.w + h[4]*x1.x + h[5]*x1.y + h[6]*x1.z + h[7]*x1.w;
  }
  #pragma unroll
  for (int k = 0; k < 15; k++){
    #pragma unroll
    for (int off = 1; off < 64; off <<= 1)
      p[k] += __shfl_xor(p[k], off);
  }
  if (lane == 0){
    float l[5], mx = -1e30f;
    #pragma unroll
    for (int k = 0; k < 5; k++){ l[k] = p[10 + k] + bmix[k]; mx = fmaxf(mx, l[k]); }
    float se = 0.f, e[5];
    #pragma unroll
    for (int k = 0; k < 5; k++){ e[k] = __expf(l[k] - mx); se += e[k]; }
    float inv = 1.0f / se, mu = 0.f, sg = 0.f;
    #pragma unroll
    for (int k = 0; k < 5; k++){
      float rho = e[k] * inv;
      mu += rho * (p[k] + bmu[k]);
      sg += rho * __expf(p[5 + k] + bvar[k]);
    }
    float a = ftanh(mu + sg * eps[(size_t)s * BATCH + row]);
    ang[row] = a;
    size_t o = ((size_t)row * SEGS + s) * 2;
    out[o]     = a;
    out[o + 1] = 0.0f;
  }
}

// ---------------- launch ----------------

extern "C" void kernel_launch(void* const* d_in, const int* in_sizes, int n_in,
                              void* d_out, int out_size, void* d_ws, size_t ws_size,
                              hipStream_t stream)
{
  const float* latent   = (const float*)d_in[0];
  const float* W_unpack = (const float*)d_in[1];
  const float* b_unpack = (const float*)d_in[2];
  const float* W_ih1    = (const float*)d_in[3];
  const float* W_hh1    = (const float*)d_in[4];
  const float* b_ih1    = (const float*)d_in[5];
  const float* b_hh1    = (const float*)d_in[6];
  const float* W_ih2    = (const float*)d_in[7];
  const float* W_hh2    = (const float*)d_in[8];
  const float* b_ih2    = (const float*)d_in[9];
  const float* b_hh2    = (const float*)d_in[10];
  const float* W_mu     = (const float*)d_in[11];
  const float* b_mu     = (const float*)d_in[12];
  const float* W_var    = (const float*)d_in[13];
  const float* b_var    = (const float*)d_in[14];
  const float* W_mix    = (const float*)d_in[15];
  const float* b_mix    = (const float*)d_in[16];
  const float* eps      = (const float*)d_in[17];
  float* out = (float*)d_out;

  char* p = (char*)d_ws;
  auto alloc = [&](size_t b) -> void* {
    void* r = (void*)p;
    p += (b + 255) & ~(size_t)255;
    return r;
  };
  short* latb  = (short*)alloc((size_t)BATCH * 512 * 2);
  short* Wub   = (short*)alloc((size_t)512 * 512 * 2);
  short* idea  = (short*)alloc((size_t)BATCH * 512 * 2);
  unsigned short* base1 = (unsigned short*)alloc((size_t)BATCH * 2048 * 2);
  short* Wr1   = (short*)alloc((size_t)2048 * 512 * 2);
  short* W1c   = (short*)alloc((size_t)2048 * 512 * 2);
  short* Wr2i  = (short*)alloc((size_t)2048 * 512 * 2);
  short* Wr2h  = (short*)alloc((size_t)2048 * 512 * 2);
  short* Whead = (short*)alloc((size_t)16 * 512 * 2);
  float* w1r   = (float*)alloc(2048 * 4);
  float* b1r   = (float*)alloc(2048 * 4);
  float* b2r   = (float*)alloc(2048 * 4);
  short* h1a   = (short*)alloc((size_t)BATCH * 512 * 2);
  short* h1b   = (short*)alloc((size_t)BATCH * 512 * 2);
  short* h2a   = (short*)alloc((size_t)BATCH * 512 * 2);
  short* h2b   = (short*)alloc((size_t)BATCH * 512 * 2);
  float* c1    = (float*)alloc((size_t)BATCH * 512 * 4);
  float* c2    = (float*)alloc((size_t)BATCH * 512 * 4);
  float* ang   = (float*)alloc(BATCH * 4);
  short* h1[2] = {h1a, h1b};
  short* h2[2] = {h2a, h2b};

  hipMemsetAsync(h1[0], 0, (size_t)BATCH * 512 * 2, stream);
  hipMemsetAsync(h2[0], 0, (size_t)BATCH * 512 * 2, stream);
  hipMemsetAsync(c1, 0, (size_t)BATCH * 512 * 4, stream);
  hipMemsetAsync(c2, 0, (size_t)BATCH * 512 * 4, stream);

  prep_cvt<<<(BATCH * 512) / 256, 256, 0, stream>>>(latent, latb, BATCH * 512);
  prep_cvt<<<(512 * 512) / 256, 256, 0, stream>>>(W_unpack, Wub, 512 * 512);
  prep_reorder<<<(2048 * 512) / 256, 256, 0, stream>>>(
      W_ih1, W_hh1, b_ih1, b_hh1, W_ih2, W_hh2, b_ih2, b_hh2,
      Wr1, W1c, Wr2i, Wr2h, w1r, b1r, b2r);
  prep_whead<<<32, 256, 0, stream>>>(W_mu, W_var, W_mix, Whead);

  dim3 blk(256);
  // idea = tanh(latent @ W_unpack^T + b_unpack)  [bf16]
  gemm_fused<<<dim3(4, 32), blk, 0, stream>>>(
      latb, Wub, nullptr, nullptr, 512, 0, 512, MODE_TANH,
      b_unpack, nullptr, nullptr, nullptr, (void*)idea,
      nullptr, nullptr, nullptr, nullptr, nullptr, nullptr, nullptr, 0);
  // base1 = idea @ W1c^T + (b_ih1 + b_hh1)   [bf16, gate-interleaved cols]
  gemm_fused<<<dim3(16, 32), blk, 0, stream>>>(
      idea, W1c, nullptr, nullptr, 512, 0, 2048, MODE_BASE,
      b1r, nullptr, nullptr, nullptr, (void*)base1,
      nullptr, nullptr, nullptr, nullptr, nullptr, nullptr, nullptr, 0);

  int cur = 0;
  for (int s = 0; s < SEGS; ++s){
    // fused head(s-1) + gates1 = base1 + ang*w1r + h1 @ Wr1^T -> cell1 -> h1', c1
    gemm_fused<<<dim3(16, 32), blk, 0, stream>>>(
        h1[cur], Wr1, nullptr, nullptr, 512, 0, 2048, MODE_CELL1,
        nullptr, base1, w1r, c1, (void*)h1[cur ^ 1],
        h2[cur], Whead, b_mu, b_var, b_mix, eps, out, s);
    // gates2 = b2r + h1' @ Wr2i^T + h2 @ Wr2h^T -> cell2 -> h2', c2
    gemm_fused<<<dim3(16, 32), blk, 0, stream>>>(
        h1[cur ^ 1], Wr2i, h2[cur], Wr2h, 512, 512, 2048, MODE_CELL2,
        b2r, nullptr, nullptr, c2, (void*)h2[cur ^ 1],
        nullptr, nullptr, nullptr, nullptr, nullptr, nullptr, nullptr, 0);
    cur ^= 1;
  }
  // final output column s=511
  head_step<<<BATCH / 4, 256, 0, stream>>>(
      h2[cur], W_mu, b_mu, W_var, b_var, W_mix, b_mix, eps, ang, out, SEGS - 1);
}